// Round 5
// baseline (785.858 us; speedup 1.0000x reference)
//
#include <hip/hip_runtime.h>

// ---------------------------------------------------------------------------
// MiniMax-M1 Lightning Attention forward, MI355X / gfx950.
//   0. cast fp32->bf16: hidden, w_qkv, w_gate (w_out cast later into dead slot)
//   1. fused qkv+gate = {silu,sigmoid}(hidden @ [w_qkv;w_gate]^T)  [N=8192]
//      epilogue: q,k row-major; kTs (x k_decay), vT via 2-pass LDS transpose;
//      gate row-major (sigmoid)
//   2. P = (q k^T) * diag_decay  per block   [2 half-launches, 1-slot P buffer]
//   3. intra = P @ v -> attn
//   4. KVT_j = vT @ kTs^T  (= KV_j^T, fp32)
//   5. scan: S_{j+1} = e^{-256 s} S_j + KV_j ; store S_j^T bf16  [512 WGs]
//   6. inter: attn += q_decay * (q @ S_j)
//   7. y = gate * rmsnorm(attn) * norm_w
//   8. out = y @ w_out^T  [fp32 -> d_out]
// Workspace: 7 slots x 33,554,432 B = 234,881,024 B peak (proven to fit).
// ---------------------------------------------------------------------------

typedef unsigned short u16;
typedef __bf16 bf16x8 __attribute__((ext_vector_type(8)));
typedef float f32x4 __attribute__((ext_vector_type(4)));

#define SEQ 4096
#define HID 2048

__device__ __forceinline__ u16 f2bf(float f) {
    union { float f; unsigned u; } v; v.f = f;
    unsigned r = v.u + 0x7fffu + ((v.u >> 16) & 1u);   // round-to-nearest-even
    return (u16)(r >> 16);
}
__device__ __forceinline__ float bf2f(u16 u) {
    union { unsigned u; float f; } v; v.u = ((unsigned)u) << 16; return v.f;
}

// async global->LDS, 16B per lane; lds dest must be wave-uniform base (+lane*16)
typedef __attribute__((address_space(1))) unsigned char gas_u8;
typedef __attribute__((address_space(3))) unsigned char las_u8;
__device__ __forceinline__ void gld16(const void* g, void* l) {
    __builtin_amdgcn_global_load_lds((gas_u8*)g, (las_u8*)l, 16, 0, 0);
}

// ---------------------------------------------------------------------------
// fp32 -> bf16 cast, 4 elems/thread, exact grids (n % 1024 == 0)
// ---------------------------------------------------------------------------
__global__ __launch_bounds__(256) void castk(const float* __restrict__ in,
                                             u16* __restrict__ out) {
    const size_t i = (size_t)blockIdx.x * 256 + threadIdx.x;
    const float4 f = *(const float4*)&in[i * 4];
    uint2 o;
    o.x = (unsigned)f2bf(f.x) | ((unsigned)f2bf(f.y) << 16);
    o.y = (unsigned)f2bf(f.z) | ((unsigned)f2bf(f.w) << 16);
    *(uint2*)&out[i * 4] = o;
}

// ---------------------------------------------------------------------------
// Generic 128x128-tile NT GEMM (C = A[MxK] * B[NxK]^T), bf16 MFMA 16x16x32.
// 256 threads = 4 waves in 2x2, each wave 64x64 via 4x4 grid of 16x16 tiles.
// Staging: global_load_lds width 16, unpadded As/Bs[128][32].
// M_QKV (fused +gate): q,k,gate row-major; kTs/vT via 2-pass LDS transpose.
// ---------------------------------------------------------------------------
#define M_QKV   0
#define M_P     2
#define M_INTRA 3
#define M_KVT   4
#define M_INTER 5
#define M_OUT   6

template <int MODE>
__global__ __launch_bounds__(256) void gemm_nt(const u16* __restrict__ A,
                                               const u16* __restrict__ Bm,
                                               void* __restrict__ Cv,
                                               const float* __restrict__ slope,
                                               int bz0,
                                               void* __restrict__ aux,
                                               void* __restrict__ aux2) {
    constexpr int KD = (MODE == M_P || MODE == M_INTER) ? 128
                     : (MODE == M_INTRA || MODE == M_KVT) ? 256 : 2048;
    const int tid = threadIdx.x;
    const int tm = blockIdx.x, tn = blockIdx.y;
    const int bzl = blockIdx.z;           // local z (P buffer index)
    const int bz  = bzl + bz0;            // global (b,h,block) index

    int bb = 0, hh = 0, jb = 0;
    if constexpr (MODE >= M_P && MODE <= M_INTER) {
        bb = bz >> 8; hh = (bz >> 4) & 15; jb = bz & 15;
    }

    if constexpr (MODE == M_P) {
        // tile fully above the (block-local) diagonal -> all zeros, skip GEMM
        if (tn > tm) {
            u16* C = (u16*)Cv + (size_t)bzl * 65536 + tm * 128 * 256 + tn * 128;
            uint4 z = make_uint4(0u, 0u, 0u, 0u);
            #pragma unroll
            for (int i = 0; i < 8; i++) {
                int f = tid + 256 * i;
                int row = f >> 4, c8 = (f & 15) * 8;
                *(uint4*)&C[row * 256 + c8] = z;
            }
            return;
        }
    }

    const u16* Ab; const u16* Bb; int lda, ldb;
    if constexpr (MODE == M_QKV || MODE == M_OUT) {
        Ab = A; lda = HID; Bb = Bm; ldb = HID;
    } else if constexpr (MODE == M_P) {
        const size_t o = ((size_t)(bb * SEQ + jb * 256)) * HID + hh * 128;
        Ab = A + o; lda = HID;                     // q rows
        Bb = Bm + o; ldb = HID;                    // k rows
    } else if constexpr (MODE == M_INTRA) {
        Ab = A + (size_t)bzl * 65536; lda = 256;   // P (local slot)
        Bb = Bm + (size_t)bz * 32768; ldb = 256;   // vT
    } else if constexpr (MODE == M_KVT) {
        Ab = A + (size_t)bz * 32768; lda = 256;    // vT
        Bb = Bm + (size_t)bz * 32768; ldb = 256;   // kTs
    } else { // M_INTER
        Ab = A + ((size_t)(bb * SEQ + jb * 256)) * HID + hh * 128; lda = HID; // q
        Bb = Bm + (size_t)bz * 16384; ldb = 128;   // S^T bf16
    }

    int kmax = KD;
    if constexpr (MODE == M_INTRA) { if (tm == 0) kmax = 128; }  // P upper half is 0

    // LDS: staging As/Bs (16,384 B); QKV also unions a [64][136] transpose
    // buffer (17,408 B) -> only QKV pays the larger footprint.
    constexpr int SMEM_ELEMS = (MODE == M_QKV) ? 64 * 136 : 8192;
    __shared__ u16 smem[SMEM_ELEMS];
    u16 (*As)[32] = (u16(*)[32])smem;
    u16 (*Bs)[32] = (u16(*)[32])(smem + 4096);

    const int lane = tid & 63, wv = tid >> 6;
    const int wm = (wv & 1) * 64, wn = (wv >> 1) * 64;
    const int quad = lane >> 4, cl = lane & 15;

    // staging addresses: wave wv covers rows [wv*32, wv*32+32) in two 16-row chunks
    const int lr = lane >> 2;            // 0..15: row within chunk
    const int lc = (lane & 3) * 8;       // 0/8/16/24: col elem offset
    const u16* gA = Ab + (size_t)(tm * 128 + wv * 32 + lr) * lda + lc;
    const u16* gB = Bb + (size_t)(tn * 128 + wv * 32 + lr) * ldb + lc;
    u16* lA = &As[wv * 32][0];           // wave-uniform LDS bases
    u16* lB = &Bs[wv * 32][0];

    f32x4 acc[4][4];
    const f32x4 zero = {0.f, 0.f, 0.f, 0.f};
    #pragma unroll
    for (int mi = 0; mi < 4; mi++)
        #pragma unroll
        for (int ni = 0; ni < 4; ni++) acc[mi][ni] = zero;

    for (int k0 = 0; k0 < kmax; k0 += 32) {
        __syncthreads();
        gld16(gA + k0,                    lA);
        gld16(gA + k0 + (size_t)16 * lda, lA + 16 * 32);
        gld16(gB + k0,                    lB);
        gld16(gB + k0 + (size_t)16 * ldb, lB + 16 * 32);
        __syncthreads();
        const int ko = quad * 8;
        bf16x8 af[4], bfv[4];
        #pragma unroll
        for (int mi = 0; mi < 4; mi++) af[mi] = *(const bf16x8*)&As[wm + mi * 16 + cl][ko];
        #pragma unroll
        for (int ni = 0; ni < 4; ni++) bfv[ni] = *(const bf16x8*)&Bs[wn + ni * 16 + cl][ko];
        #pragma unroll
        for (int mi = 0; mi < 4; mi++)
            #pragma unroll
            for (int ni = 0; ni < 4; ni++)
                acc[mi][ni] = __builtin_amdgcn_mfma_f32_16x16x32_bf16(af[mi], bfv[ni], acc[mi][ni], 0, 0, 0);
    }

    if constexpr (MODE == M_QKV) {
        const int which = tn >> 4, hd = tn & 15;
        if (which == 3) {
            // gate: sigmoid, row-major
            #pragma unroll
            for (int mi = 0; mi < 4; mi++)
                #pragma unroll
                for (int ni = 0; ni < 4; ni++)
                    #pragma unroll
                    for (int r = 0; r < 4; r++) {
                        const int m = tm * 128 + wm + mi * 16 + quad * 4 + r;
                        const int n = hd * 128 + wn + ni * 16 + cl;
                        const float x = acc[mi][ni][r];
                        ((u16*)aux2)[(size_t)m * HID + n] = f2bf(1.f / (1.f + __expf(-x)));
                    }
            return;
        }
        if (which == 0) {
            // q: silu, row-major
            #pragma unroll
            for (int mi = 0; mi < 4; mi++)
                #pragma unroll
                for (int ni = 0; ni < 4; ni++)
                    #pragma unroll
                    for (int r = 0; r < 4; r++) {
                        const int m = tm * 128 + wm + mi * 16 + quad * 4 + r;
                        const int n = hd * 128 + wn + ni * 16 + cl;
                        const float x = acc[mi][ni][r];
                        ((u16*)Cv)[(size_t)m * HID + n] = f2bf(x / (1.f + __expf(-x)));
                    }
            return;
        }
        // which==1 (k): row-major silu + decayed transpose -> kTs
        // which==2 (v): transposed silu -> vT
        const int bbq = tm >> 5, jbq = (tm >> 1) & 15, half = tm & 1;
        const size_t bzq = (size_t)(bbq * 256 + hd * 16 + jbq);
        u16* tdst = (which == 1 ? (u16*)Cv + (size_t)2 * 16777216 : (u16*)aux)
                    + bzq * 32768 + half * 128;
        float dec[4][4];
        if (which == 1) {
            const float s_ = slope[hd];
            #pragma unroll
            for (int mi = 0; mi < 4; mi++)
                #pragma unroll
                for (int r = 0; r < 4; r++) {
                    const int minb = half * 128 + wm + mi * 16 + quad * 4 + r;
                    dec[mi][r] = __expf(-s_ * (float)(255 - minb));
                }
            // row-major k (undecayed)
            #pragma unroll
            for (int mi = 0; mi < 4; mi++)
                #pragma unroll
                for (int ni = 0; ni < 4; ni++)
                    #pragma unroll
                    for (int r = 0; r < 4; r++) {
                        const int m = tm * 128 + wm + mi * 16 + quad * 4 + r;
                        const int n = hd * 128 + wn + ni * 16 + cl;
                        const float x = acc[mi][ni][r];
                        ((u16*)Cv)[(size_t)16777216 + (size_t)m * HID + n] =
                            f2bf(x / (1.f + __expf(-x)));
                    }
        }
        // two-pass transpose over d-halves through [64][136] buffer
        u16 (*Tr)[136] = (u16(*)[136])smem;
        #pragma unroll
        for (int dh = 0; dh < 2; dh++) {
            __syncthreads();   // staging/previous-pass LDS reads done
            if ((wv >> 1) == dh) {
                #pragma unroll
                for (int mi = 0; mi < 4; mi++)
                    #pragma unroll
                    for (int ni = 0; ni < 4; ni++) {
                        u16 p[4];
                        #pragma unroll
                        for (int r = 0; r < 4; r++) {
                            const float x = acc[mi][ni][r];
                            const float s = x / (1.f + __expf(-x));
                            p[r] = f2bf(which == 1 ? s * dec[mi][r] : s);
                        }
                        uint2 pk;
                        pk.x = (unsigned)p[0] | ((unsigned)p[1] << 16);
                        pk.y = (unsigned)p[2] | ((unsigned)p[3] << 16);
                        *(uint2*)&Tr[ni * 16 + cl][wm + mi * 16 + quad * 4] = pk;
                    }
            }
            __syncthreads();
            #pragma unroll
            for (int i = 0; i < 4; i++) {
                const int flat = tid + 256 * i;
                const int dl = flat >> 4, mc = (flat & 15) * 8;
                *(uint4*)&tdst[(size_t)(dh * 64 + dl) * 256 + mc] = *(const uint4*)&Tr[dl][mc];
            }
        }
        return;
    }

    float sl = 0.f;
    if constexpr (MODE == M_P || MODE == M_INTER) sl = slope[hh];

    #pragma unroll
    for (int mi = 0; mi < 4; mi++) {
        #pragma unroll
        for (int ni = 0; ni < 4; ni++) {
            const f32x4 v = acc[mi][ni];
            #pragma unroll
            for (int r = 0; r < 4; r++) {
                const int m = tm * 128 + wm + mi * 16 + quad * 4 + r;  // C row (A index)
                const int n = tn * 128 + wn + ni * 16 + cl;            // C col (B index)
                const float x = v[r];
                if constexpr (MODE == M_P) {
                    const int d = m - n;
                    ((u16*)Cv)[(size_t)bzl * 65536 + m * 256 + n] =
                        f2bf(d >= 0 ? x * __expf(-sl * (float)d) : 0.f);
                } else if constexpr (MODE == M_INTRA) {
                    ((u16*)Cv)[((size_t)(bb * SEQ + jb * 256 + m)) * HID + hh * 128 + n] = f2bf(x);
                } else if constexpr (MODE == M_KVT) {
                    ((float*)Cv)[(size_t)bz * 16384 + m * 128 + n] = x;
                } else if constexpr (MODE == M_INTER) {
                    u16* C = (u16*)Cv + ((size_t)(bb * SEQ + jb * 256 + m)) * HID + hh * 128 + n;
                    *C = f2bf(bf2f(*C) + __expf(-sl * (float)(m + 1)) * x);  // += q_decay * inter
                } else { // M_OUT
                    ((float*)Cv)[(size_t)m * HID + n] = x;
                }
            }
        }
    }
}

// ---------------------------------------------------------------------------
// S_0 = 0; write S_j^T (bf16); S_{j+1} = e^{-256 s} S_j + KV_j
// 512 WGs: (b,h) x 16 column-chunks; serial only over j.
// ---------------------------------------------------------------------------
__global__ __launch_bounds__(256) void scan_kv(const float* __restrict__ KVT,
                                               u16* __restrict__ ST,
                                               const float* __restrict__ slope) {
    const int bh = blockIdx.x >> 4, ch = blockIdx.x & 15;
    const int off = ch * 1024 + threadIdx.x * 4;
    const float bd = __expf(-256.f * slope[bh & 15]);
    float4 st = {0.f, 0.f, 0.f, 0.f};
    for (int j = 0; j < 16; j++) {
        const size_t base = ((size_t)(bh * 16 + j)) * 16384 + off;
        uint2 o;
        o.x = (unsigned)f2bf(st.x) | ((unsigned)f2bf(st.y) << 16);
        o.y = (unsigned)f2bf(st.z) | ((unsigned)f2bf(st.w) << 16);
        *(uint2*)&ST[base] = o;
        const float4 kv = *(const float4*)&KVT[base];
        st.x = bd * st.x + kv.x;
        st.y = bd * st.y + kv.y;
        st.z = bd * st.z + kv.z;
        st.w = bd * st.w + kv.w;
    }
}

// ---------------------------------------------------------------------------
// y = gate * (attn * rsqrt(mean(attn^2)+eps)) * norm_w   (one WG per row)
// ---------------------------------------------------------------------------
__global__ __launch_bounds__(256) void rmsnorm_gate(const u16* __restrict__ attn,
                                                    const u16* __restrict__ gate,
                                                    const float* __restrict__ nw,
                                                    u16* __restrict__ y) {
    const int r = blockIdx.x, tid = threadIdx.x;
    const size_t base = (size_t)r * HID + tid * 8;
    const uint4 a = *(const uint4*)&attn[base];
    float x[8];
    x[0] = bf2f(a.x & 0xffff); x[1] = bf2f(a.x >> 16);
    x[2] = bf2f(a.y & 0xffff); x[3] = bf2f(a.y >> 16);
    x[4] = bf2f(a.z & 0xffff); x[5] = bf2f(a.z >> 16);
    x[6] = bf2f(a.w & 0xffff); x[7] = bf2f(a.w >> 16);
    float s = 0.f;
    #pragma unroll
    for (int i = 0; i < 8; i++) s += x[i] * x[i];
    #pragma unroll
    for (int off = 32; off > 0; off >>= 1) s += __shfl_down(s, off);
    __shared__ float red[4];
    if ((tid & 63) == 0) red[tid >> 6] = s;
    __syncthreads();
    const float tot = red[0] + red[1] + red[2] + red[3];
    const float sc = rsqrtf(tot * (1.f / 2048.f) + 1e-6f);
    const uint4 g = *(const uint4*)&gate[base];
    float gv[8];
    gv[0] = bf2f(g.x & 0xffff); gv[1] = bf2f(g.x >> 16);
    gv[2] = bf2f(g.y & 0xffff); gv[3] = bf2f(g.y >> 16);
    gv[4] = bf2f(g.z & 0xffff); gv[5] = bf2f(g.z >> 16);
    gv[6] = bf2f(g.w & 0xffff); gv[7] = bf2f(g.w >> 16);
    const float4 w0 = *(const float4*)&nw[tid * 8];
    const float4 w1 = *(const float4*)&nw[tid * 8 + 4];
    const float wv[8] = {w0.x, w0.y, w0.z, w0.w, w1.x, w1.y, w1.z, w1.w};
    u16 o[8];
    #pragma unroll
    for (int i = 0; i < 8; i++) o[i] = f2bf(gv[i] * x[i] * sc * wv[i]);
    uint4 ov;
    ov.x = (unsigned)o[0] | ((unsigned)o[1] << 16);
    ov.y = (unsigned)o[2] | ((unsigned)o[3] << 16);
    ov.z = (unsigned)o[4] | ((unsigned)o[5] << 16);
    ov.w = (unsigned)o[6] | ((unsigned)o[7] << 16);
    *(uint4*)&y[base] = ov;
}

// ---------------------------------------------------------------------------
extern "C" void kernel_launch(void* const* d_in, const int* in_sizes, int n_in,
                              void* d_out, int out_size, void* d_ws, size_t ws_size,
                              hipStream_t stream) {
    const float* hidden = (const float*)d_in[0];
    const float* slope  = (const float*)d_in[1];
    const float* w_qkv  = (const float*)d_in[2];
    const float* w_gate = (const float*)d_in[3];
    const float* w_out  = (const float*)d_in[4];
    const float* norm_w = (const float*)d_in[5];
    float* out = (float*)d_out;

    // 7 slots x 33,554,432 B = 234,881,024 B total
    char* w = (char*)d_ws;
    u16* qb   = (u16*)(w);                 // S0: q                 [QKV .. inter]
    u16* kb   = (u16*)(w +  33554432);     // S1: k                 [QKV .. P#2]
    u16* kTs  = (u16*)(w +  67108864);     // S2: kTs (via QKV)     [QKV .. KVT]
    u16* hid_bf = (u16*)(w + 100663296);   // S3: hidden bf16       [cast .. QKV]
    u16* vT   = (u16*)(w + 134217728);     // S4: vT (via QKV)      [QKV .. KVT]
    u16* gate = (u16*)(w + 167772160);     // S5: gate (via QKV)    [QKV .. rms]
    u16* wqkv_bf  = (u16*)(w + 201326592); // S6: w_qkv bf16 25.17M [cast .. QKV]
    u16* wgate_bf = (u16*)(w + 201326592 + 25165824); // S6 tail 8.39M, contiguous
    // aliases (disjoint lifetimes):
    u16*   P    = hid_bf;                  // S3: P half            [P .. intra]
    float* KVT  = (float*)kb;              // S1: KV^T fp32         [KVT .. scan]
    u16*   ST   = hid_bf;                  // S3: S^T bf16          [scan .. inter]
    u16*   wout_bf = kb;                   // S1: w_out bf16        [cast(after scan) .. OUT]
    u16*   attn = wqkv_bf;                 // S6: attn              [intra .. rms]
    u16*   y    = kTs;                     // S2: y                 [rms .. OUT]

    castk<<<16384, 256, 0, stream>>>(hidden, hid_bf);
    castk<<<12288, 256, 0, stream>>>(w_qkv,  wqkv_bf);
    castk<<< 4096, 256, 0, stream>>>(w_gate, wgate_bf);

    // fused qkv+gate: B = [w_qkv ; w_gate] (8192 x 2048 contiguous)
    gemm_nt<M_QKV ><<<dim3(64, 64, 1),  256, 0, stream>>>(hid_bf, wqkv_bf, qb, slope, 0, vT, gate);
    gemm_nt<M_P   ><<<dim3(2, 2, 256),  256, 0, stream>>>(qb, kb, P, slope, 0, nullptr, nullptr);
    gemm_nt<M_INTRA><<<dim3(2, 1, 256), 256, 0, stream>>>(P, vT, attn, slope, 0, nullptr, nullptr);
    gemm_nt<M_P   ><<<dim3(2, 2, 256),  256, 0, stream>>>(qb, kb, P, slope, 256, nullptr, nullptr);
    gemm_nt<M_INTRA><<<dim3(2, 1, 256), 256, 0, stream>>>(P, vT, attn, slope, 256, nullptr, nullptr);
    gemm_nt<M_KVT ><<<dim3(1, 1, 512),  256, 0, stream>>>(vT, kTs, KVT, slope, 0, nullptr, nullptr);
    scan_kv         <<<512,             256, 0, stream>>>(KVT, ST, slope);
    castk<<< 4096, 256, 0, stream>>>(w_out, wout_bf);
    gemm_nt<M_INTER><<<dim3(2, 1, 512), 256, 0, stream>>>(qb, ST, attn, slope, 0, nullptr, nullptr);
    rmsnorm_gate    <<<8192,            256, 0, stream>>>(attn, gate, norm_w, y);
    gemm_nt<M_OUT ><<<dim3(64, 16, 1),  256, 0, stream>>>(y, wout_bf, out, slope, 0, nullptr, nullptr);
}

// Round 6
// 768.369 us; speedup vs baseline: 1.0228x; 1.0228x over previous
//
#include <hip/hip_runtime.h>

// ---------------------------------------------------------------------------
// MiniMax-M1 Lightning Attention forward, MI355X / gfx950.
//   0. cast fp32->bf16: hidden, w_qkv(+w_gate contiguous)
//   1. fused qkv+gate = {silu,sigmoid}(hidden @ [w_qkv;w_gate]^T)  [N=8192]
//      epilogue (lean): q,k,gate row-major; v stored DIRECTLY transposed (vT)
//      via per-lane uint2 stores (C-layout gives 4 consecutive m at fixed d)
//   2. transpose_k: kTs[d][m] = silu_k[m][d] * exp(-s*(255-m))
//   3. KVT_j = vT @ kTs^T  (= KV_j^T, fp32)
//   4. scan: S_{j+1} = e^{-256 s} S_j + KV_j ; store S_j^T bf16  [512 WGs]
//   5. P = (q k^T) * diag_decay  per block   [2 half-launches, 1-slot P buffer]
//   6. intra+inter fused: acc = q @ S^T; acc *= q_decay(row); acc += P @ v
//      -> attn (single bf16 store, no RMW)
//   7. y = gate * rmsnorm(attn) * norm_w
//   8. out = y @ w_out^T  [fp32 -> d_out]
// Workspace: 7 slots x 33,554,432 B = 234,881,024 B peak (proven to fit).
// ---------------------------------------------------------------------------

typedef unsigned short u16;
typedef __bf16 bf16x8 __attribute__((ext_vector_type(8)));
typedef float f32x4 __attribute__((ext_vector_type(4)));

#define SEQ 4096
#define HID 2048

__device__ __forceinline__ u16 f2bf(float f) {
    union { float f; unsigned u; } v; v.f = f;
    unsigned r = v.u + 0x7fffu + ((v.u >> 16) & 1u);   // round-to-nearest-even
    return (u16)(r >> 16);
}
__device__ __forceinline__ float bf2f(u16 u) {
    union { unsigned u; float f; } v; v.u = ((unsigned)u) << 16; return v.f;
}

// async global->LDS, 16B per lane; lds dest must be wave-uniform base (+lane*16)
typedef __attribute__((address_space(1))) unsigned char gas_u8;
typedef __attribute__((address_space(3))) unsigned char las_u8;
__device__ __forceinline__ void gld16(const void* g, void* l) {
    __builtin_amdgcn_global_load_lds((gas_u8*)g, (las_u8*)l, 16, 0, 0);
}

// ---------------------------------------------------------------------------
// fp32 -> bf16 cast, 4 elems/thread, exact grids (n % 1024 == 0)
// ---------------------------------------------------------------------------
__global__ __launch_bounds__(256) void castk(const float* __restrict__ in,
                                             u16* __restrict__ out) {
    const size_t i = (size_t)blockIdx.x * 256 + threadIdx.x;
    const float4 f = *(const float4*)&in[i * 4];
    uint2 o;
    o.x = (unsigned)f2bf(f.x) | ((unsigned)f2bf(f.y) << 16);
    o.y = (unsigned)f2bf(f.z) | ((unsigned)f2bf(f.w) << 16);
    *(uint2*)&out[i * 4] = o;
}

// ---------------------------------------------------------------------------
// Generic 128x128-tile NT GEMM (C = A[MxK] * B[NxK]^T), bf16 MFMA 16x16x32.
// 256 threads = 4 waves in 2x2, each wave 64x64 via 4x4 grid of 16x16 tiles.
// Staging: global_load_lds width 16, unpadded As/Bs[128][32].
// M_INTRA runs two phases: (q @ S^T), row-scale by q_decay, += (P @ v).
// ---------------------------------------------------------------------------
#define M_QKV   0
#define M_P     2
#define M_INTRA 3
#define M_KVT   4
#define M_OUT   6

template <int MODE>
__global__ __launch_bounds__(256) void gemm_nt(const u16* __restrict__ A,
                                               const u16* __restrict__ Bm,
                                               void* __restrict__ Cv,
                                               const float* __restrict__ slope,
                                               int bz0,
                                               void* __restrict__ aux,
                                               void* __restrict__ aux2) {
    constexpr int NPH = (MODE == M_INTRA) ? 2 : 1;
    const int tid = threadIdx.x;
    const int tm = blockIdx.x, tn = blockIdx.y;
    const int bzl = blockIdx.z;           // local z (P buffer index)
    const int bz  = bzl + bz0;            // global (b,h,block) index

    int bb = 0, hh = 0, jb = 0;
    if constexpr (MODE == M_P || MODE == M_INTRA || MODE == M_KVT) {
        bb = bz >> 8; hh = (bz >> 4) & 15; jb = bz & 15;
    }

    if constexpr (MODE == M_P) {
        // tile fully above the (block-local) diagonal -> all zeros, skip GEMM
        if (tn > tm) {
            u16* C = (u16*)Cv + (size_t)bzl * 65536 + tm * 128 * 256 + tn * 128;
            uint4 z = make_uint4(0u, 0u, 0u, 0u);
            #pragma unroll
            for (int i = 0; i < 8; i++) {
                int f = tid + 256 * i;
                int row = f >> 4, c8 = (f & 15) * 8;
                *(uint4*)&C[row * 256 + c8] = z;
            }
            return;
        }
    }

    __shared__ u16 smem[8192];            // As/Bs staging, 16,384 B
    u16 (*As)[32] = (u16(*)[32])smem;
    u16 (*Bs)[32] = (u16(*)[32])(smem + 4096);

    const int lane = tid & 63, wv = tid >> 6;
    const int wm = (wv & 1) * 64, wn = (wv >> 1) * 64;
    const int quad = lane >> 4, cl = lane & 15;
    const int lr = lane >> 2;            // 0..15: row within 16-row chunk
    const int lc = (lane & 3) * 8;       // 0/8/16/24: col elem offset
    u16* lA = &As[wv * 32][0];           // wave-uniform LDS bases
    u16* lB = &Bs[wv * 32][0];

    f32x4 acc[4][4];
    const f32x4 zero = {0.f, 0.f, 0.f, 0.f};
    #pragma unroll
    for (int mi = 0; mi < 4; mi++)
        #pragma unroll
        for (int ni = 0; ni < 4; ni++) acc[mi][ni] = zero;

    #pragma unroll
    for (int ph = 0; ph < NPH; ph++) {
        const u16* Ab; const u16* Bb; int lda, ldb, kmax;
        if constexpr (MODE == M_QKV || MODE == M_OUT) {
            Ab = A; lda = HID; Bb = Bm; ldb = HID; kmax = 2048;
        } else if constexpr (MODE == M_P) {
            const size_t o = ((size_t)(bb * SEQ + jb * 256)) * HID + hh * 128;
            Ab = A + o; lda = HID;                     // q rows
            Bb = Bm + o; ldb = HID;                    // k rows
            kmax = 128;
        } else if constexpr (MODE == M_KVT) {
            Ab = A + (size_t)bz * 32768; lda = 256;    // vT
            Bb = Bm + (size_t)bz * 32768; ldb = 256;   // kTs
            kmax = 256;
        } else { // M_INTRA
            if (ph == 0) {  // inter: q @ S^T
                Ab = A + ((size_t)(bb * SEQ + jb * 256)) * HID + hh * 128; lda = HID;
                Bb = Bm + (size_t)bz * 16384; ldb = 128;   // S^T bf16
                kmax = 128;
            } else {        // intra: P @ v
                Ab = (const u16*)aux + (size_t)bzl * 65536; lda = 256;   // P
                Bb = (const u16*)aux2 + (size_t)bz * 32768; ldb = 256;   // vT
                kmax = (tm == 0) ? 128 : 256;          // P upper half is 0
            }
        }
        const u16* gA = Ab + (size_t)(tm * 128 + wv * 32 + lr) * lda + lc;
        const u16* gB = Bb + (size_t)(tn * 128 + wv * 32 + lr) * ldb + lc;

        for (int k0 = 0; k0 < kmax; k0 += 32) {
            __syncthreads();
            gld16(gA + k0,                    lA);
            gld16(gA + k0 + (size_t)16 * lda, lA + 16 * 32);
            gld16(gB + k0,                    lB);
            gld16(gB + k0 + (size_t)16 * ldb, lB + 16 * 32);
            __syncthreads();
            const int ko = quad * 8;
            bf16x8 af[4], bfv[4];
            #pragma unroll
            for (int mi = 0; mi < 4; mi++) af[mi] = *(const bf16x8*)&As[wm + mi * 16 + cl][ko];
            #pragma unroll
            for (int ni = 0; ni < 4; ni++) bfv[ni] = *(const bf16x8*)&Bs[wn + ni * 16 + cl][ko];
            #pragma unroll
            for (int mi = 0; mi < 4; mi++)
                #pragma unroll
                for (int ni = 0; ni < 4; ni++)
                    acc[mi][ni] = __builtin_amdgcn_mfma_f32_16x16x32_bf16(af[mi], bfv[ni], acc[mi][ni], 0, 0, 0);
        }

        if constexpr (MODE == M_INTRA) {
            if (ph == 0) {   // scale inter part by q_decay(row)
                const float s_ = slope[hh];
                #pragma unroll
                for (int mi = 0; mi < 4; mi++)
                    #pragma unroll
                    for (int r = 0; r < 4; r++) {
                        const int m = tm * 128 + wm + mi * 16 + quad * 4 + r;
                        const float qd = __expf(-s_ * (float)(m + 1));
                        #pragma unroll
                        for (int ni = 0; ni < 4; ni++) acc[mi][ni][r] *= qd;
                    }
            }
        }
    }

    if constexpr (MODE == M_QKV) {
        // tn 0-15: q | 16-31: k | 32-47: v (direct transposed) | 48-63: gate
        const int which = tn >> 4, hd = tn & 15;
        if (which == 2) {
            // vT[bzq][d][m]: lane holds 4 consecutive m at fixed d -> uint2
            const int bbq = tm >> 5, jbq = (tm >> 1) & 15, half = tm & 1;
            const size_t bzq = (size_t)(bbq * 256 + hd * 16 + jbq);
            u16* tdst = (u16*)aux + bzq * 32768 + half * 128;
            const int mloc = wm + (quad << 2);   // m within 128-half (consec 4)
            #pragma unroll
            for (int mi = 0; mi < 4; mi++)
                #pragma unroll
                for (int ni = 0; ni < 4; ni++) {
                    const int d = wn + ni * 16 + cl;
                    u16 p[4];
                    #pragma unroll
                    for (int r = 0; r < 4; r++) {
                        const float x = acc[mi][ni][r];
                        p[r] = f2bf(x / (1.f + __expf(-x)));
                    }
                    uint2 pk;
                    pk.x = (unsigned)p[0] | ((unsigned)p[1] << 16);
                    pk.y = (unsigned)p[2] | ((unsigned)p[3] << 16);
                    *(uint2*)&tdst[(size_t)d * 256 + mloc + mi * 16] = pk;
                }
            return;
        }
        u16* dst = (which == 0) ? (u16*)Cv
                 : (which == 1) ? (u16*)Cv + (size_t)16777216   // k slot (S1)
                                : (u16*)aux2;                   // gate slot
        #pragma unroll
        for (int mi = 0; mi < 4; mi++)
            #pragma unroll
            for (int ni = 0; ni < 4; ni++)
                #pragma unroll
                for (int r = 0; r < 4; r++) {
                    const int m = tm * 128 + wm + mi * 16 + quad * 4 + r;
                    const int n = hd * 128 + wn + ni * 16 + cl;
                    const float x = acc[mi][ni][r];
                    const float v = (which == 3) ? 1.f / (1.f + __expf(-x))
                                                 : x / (1.f + __expf(-x));
                    dst[(size_t)m * HID + n] = f2bf(v);
                }
        return;
    }

    float sl = 0.f;
    if constexpr (MODE == M_P) sl = slope[hh];

    #pragma unroll
    for (int mi = 0; mi < 4; mi++) {
        #pragma unroll
        for (int ni = 0; ni < 4; ni++) {
            const f32x4 v = acc[mi][ni];
            #pragma unroll
            for (int r = 0; r < 4; r++) {
                const int m = tm * 128 + wm + mi * 16 + quad * 4 + r;  // C row (A index)
                const int n = tn * 128 + wn + ni * 16 + cl;            // C col (B index)
                const float x = v[r];
                if constexpr (MODE == M_P) {
                    const int d = m - n;
                    ((u16*)Cv)[(size_t)bzl * 65536 + m * 256 + n] =
                        f2bf(d >= 0 ? x * __expf(-sl * (float)d) : 0.f);
                } else if constexpr (MODE == M_INTRA) {
                    ((u16*)Cv)[((size_t)(bb * SEQ + jb * 256 + m)) * HID + hh * 128 + n] = f2bf(x);
                } else if constexpr (MODE == M_KVT) {
                    ((float*)Cv)[(size_t)bz * 16384 + m * 128 + n] = x;
                } else { // M_OUT
                    ((float*)Cv)[(size_t)m * HID + n] = x;
                }
            }
        }
    }
}

// ---------------------------------------------------------------------------
// Per (b,h,block): kTs[d][m] = k[m][d] * exp(-s*(255-m))  (vectorized stores)
// ---------------------------------------------------------------------------
__global__ __launch_bounds__(256) void transpose_k(const u16* __restrict__ kb,
                                                   u16* __restrict__ kTs,
                                                   const float* __restrict__ slope) {
    __shared__ u16 t[128][137];   // pad 137: transposed-read lanes land 2-way max
    const int bz = blockIdx.x;
    const int bb = bz >> 8, hh = (bz >> 4) & 15, jb = bz & 15;
    const int tid = threadIdx.x;
    const float s_ = slope[hh];
    const u16* src = kb + ((size_t)(bb * SEQ + jb * 256)) * HID + hh * 128;
    u16* dst = kTs + (size_t)bz * 32768;

    for (int half = 0; half < 2; half++) {
        #pragma unroll
        for (int i = 0; i < 8; i++) {
            const int flat = tid + 256 * i;
            const int row = flat >> 4, c8 = (flat & 15) * 8;
            *(uint4*)&t[row][c8] = *(const uint4*)&src[(size_t)(half * 128 + row) * HID + c8];
        }
        __syncthreads();
        #pragma unroll
        for (int i = 0; i < 8; i++) {
            const int flat = tid + 256 * i;
            const int d = flat >> 4, mc = (flat & 15) * 8;
            u16 p[8];
            #pragma unroll
            for (int j = 0; j < 8; j++) {
                const int m = half * 128 + mc + j;
                p[j] = f2bf(bf2f(t[mc + j][d]) * __expf(-s_ * (float)(255 - m)));
            }
            uint4 pk;
            pk.x = (unsigned)p[0] | ((unsigned)p[1] << 16);
            pk.y = (unsigned)p[2] | ((unsigned)p[3] << 16);
            pk.z = (unsigned)p[4] | ((unsigned)p[5] << 16);
            pk.w = (unsigned)p[6] | ((unsigned)p[7] << 16);
            *(uint4*)&dst[(size_t)d * 256 + half * 128 + mc] = pk;
        }
        __syncthreads();
    }
}

// ---------------------------------------------------------------------------
// S_0 = 0; write S_j^T (bf16); S_{j+1} = e^{-256 s} S_j + KV_j
// 512 WGs: (b,h) x 16 column-chunks; serial only over j.
// ---------------------------------------------------------------------------
__global__ __launch_bounds__(256) void scan_kv(const float* __restrict__ KVT,
                                               u16* __restrict__ ST,
                                               const float* __restrict__ slope) {
    const int bh = blockIdx.x >> 4, ch = blockIdx.x & 15;
    const int off = ch * 1024 + threadIdx.x * 4;
    const float bd = __expf(-256.f * slope[bh & 15]);
    float4 st = {0.f, 0.f, 0.f, 0.f};
    for (int j = 0; j < 16; j++) {
        const size_t base = ((size_t)(bh * 16 + j)) * 16384 + off;
        uint2 o;
        o.x = (unsigned)f2bf(st.x) | ((unsigned)f2bf(st.y) << 16);
        o.y = (unsigned)f2bf(st.z) | ((unsigned)f2bf(st.w) << 16);
        *(uint2*)&ST[base] = o;
        const float4 kv = *(const float4*)&KVT[base];
        st.x = bd * st.x + kv.x;
        st.y = bd * st.y + kv.y;
        st.z = bd * st.z + kv.z;
        st.w = bd * st.w + kv.w;
    }
}

// ---------------------------------------------------------------------------
// y = gate * (attn * rsqrt(mean(attn^2)+eps)) * norm_w   (one WG per row)
// ---------------------------------------------------------------------------
__global__ __launch_bounds__(256) void rmsnorm_gate(const u16* __restrict__ attn,
                                                    const u16* __restrict__ gate,
                                                    const float* __restrict__ nw,
                                                    u16* __restrict__ y) {
    const int r = blockIdx.x, tid = threadIdx.x;
    const size_t base = (size_t)r * HID + tid * 8;
    const uint4 a = *(const uint4*)&attn[base];
    float x[8];
    x[0] = bf2f(a.x & 0xffff); x[1] = bf2f(a.x >> 16);
    x[2] = bf2f(a.y & 0xffff); x[3] = bf2f(a.y >> 16);
    x[4] = bf2f(a.z & 0xffff); x[5] = bf2f(a.z >> 16);
    x[6] = bf2f(a.w & 0xffff); x[7] = bf2f(a.w >> 16);
    float s = 0.f;
    #pragma unroll
    for (int i = 0; i < 8; i++) s += x[i] * x[i];
    #pragma unroll
    for (int off = 32; off > 0; off >>= 1) s += __shfl_down(s, off);
    __shared__ float red[4];
    if ((tid & 63) == 0) red[tid >> 6] = s;
    __syncthreads();
    const float tot = red[0] + red[1] + red[2] + red[3];
    const float sc = rsqrtf(tot * (1.f / 2048.f) + 1e-6f);
    const uint4 g = *(const uint4*)&gate[base];
    float gv[8];
    gv[0] = bf2f(g.x & 0xffff); gv[1] = bf2f(g.x >> 16);
    gv[2] = bf2f(g.y & 0xffff); gv[3] = bf2f(g.y >> 16);
    gv[4] = bf2f(g.z & 0xffff); gv[5] = bf2f(g.z >> 16);
    gv[6] = bf2f(g.w & 0xffff); gv[7] = bf2f(g.w >> 16);
    const float4 w0 = *(const float4*)&nw[tid * 8];
    const float4 w1 = *(const float4*)&nw[tid * 8 + 4];
    const float wv[8] = {w0.x, w0.y, w0.z, w0.w, w1.x, w1.y, w1.z, w1.w};
    u16 o[8];
    #pragma unroll
    for (int i = 0; i < 8; i++) o[i] = f2bf(gv[i] * x[i] * sc * wv[i]);
    uint4 ov;
    ov.x = (unsigned)o[0] | ((unsigned)o[1] << 16);
    ov.y = (unsigned)o[2] | ((unsigned)o[3] << 16);
    ov.z = (unsigned)o[4] | ((unsigned)o[5] << 16);
    ov.w = (unsigned)o[6] | ((unsigned)o[7] << 16);
    *(uint4*)&y[base] = ov;
}

// ---------------------------------------------------------------------------
extern "C" void kernel_launch(void* const* d_in, const int* in_sizes, int n_in,
                              void* d_out, int out_size, void* d_ws, size_t ws_size,
                              hipStream_t stream) {
    const float* hidden = (const float*)d_in[0];
    const float* slope  = (const float*)d_in[1];
    const float* w_qkv  = (const float*)d_in[2];
    const float* w_gate = (const float*)d_in[3];
    const float* w_out  = (const float*)d_in[4];
    const float* norm_w = (const float*)d_in[5];
    float* out = (float*)d_out;

    // 7 slots x 33,554,432 B = 234,881,024 B total
    char* w = (char*)d_ws;
    u16* qb   = (u16*)(w);                 // S0: q                 [QKV .. intra#2]
    u16* kb   = (u16*)(w +  33554432);     // S1: k                 [QKV .. P#2]
    u16* kTs  = (u16*)(w +  67108864);     // S2: kTs               [transpose .. KVT]
    u16* hid_bf = (u16*)(w + 100663296);   // S3: hidden bf16       [cast .. QKV]
    u16* vT   = (u16*)(w + 134217728);     // S4: vT (via QKV)      [QKV .. intra#2]
    u16* gate = (u16*)(w + 167772160);     // S5: gate (via QKV)    [QKV .. rms]
    u16* wqkv_bf  = (u16*)(w + 201326592); // S6: w_qkv bf16 25.17M [cast .. QKV]
    u16* wgate_bf = (u16*)(w + 201326592 + 25165824); // S6 tail 8.39M, contiguous
    // aliases (disjoint lifetimes):
    float* KVT  = (float*)hid_bf;          // S3: KV^T fp32         [KVT .. scan]
    u16*   ST   = kTs;                     // S2: S^T bf16 16.8M    [scan .. intra#2]
    u16*   P    = hid_bf;                  // S3: P half            [P#1 .. intra#2]
    u16*   wout_bf = kb;                   // S1: w_out bf16        [cast .. OUT]
    u16*   attn = wqkv_bf;                 // S6: attn              [intra#1 .. rms]
    u16*   y    = kTs;                     // S2: y                 [rms .. OUT]

    castk<<<16384, 256, 0, stream>>>(hidden, hid_bf);
    castk<<<12288, 256, 0, stream>>>(w_qkv,  wqkv_bf);
    castk<<< 4096, 256, 0, stream>>>(w_gate, wgate_bf);

    // fused qkv+gate: B = [w_qkv ; w_gate] (8192 x 2048 contiguous)
    gemm_nt<M_QKV ><<<dim3(64, 64, 1),  256, 0, stream>>>(hid_bf, wqkv_bf, qb, slope, 0, vT, gate);
    transpose_k     <<<512,             256, 0, stream>>>(kb, kTs, slope);
    gemm_nt<M_KVT ><<<dim3(1, 1, 512),  256, 0, stream>>>(vT, kTs, KVT, slope, 0, nullptr, nullptr);
    scan_kv         <<<512,             256, 0, stream>>>(KVT, ST, slope);
    gemm_nt<M_P   ><<<dim3(2, 2, 256),  256, 0, stream>>>(qb, kb, P, slope, 0, nullptr, nullptr);
    gemm_nt<M_INTRA><<<dim3(2, 1, 256), 256, 0, stream>>>(qb, ST, attn, slope, 0, P, vT);
    gemm_nt<M_P   ><<<dim3(2, 2, 256),  256, 0, stream>>>(qb, kb, P, slope, 256, nullptr, nullptr);
    gemm_nt<M_INTRA><<<dim3(2, 1, 256), 256, 0, stream>>>(qb, ST, attn, slope, 256, P, vT);
    castk<<< 4096, 256, 0, stream>>>(w_out, wout_bf);
    rmsnorm_gate    <<<8192,            256, 0, stream>>>(attn, gate, norm_w, y);
    gemm_nt<M_OUT ><<<dim3(64, 16, 1),  256, 0, stream>>>(y, wout_bf, out, slope, 0, nullptr, nullptr);
}